// Round 4
// baseline (7044.356 us; speedup 1.0000x reference)
//
#include <hip/hip_runtime.h>
#include <math.h>

#define NSW 12  // one-sided works on implicit X^2: extra sweeps vs the two-sided kernel

__device__ __forceinline__ float bperm_f(int addr4, float v) {
    return __int_as_float(__builtin_amdgcn_ds_bpermute(addr4, __float_as_int(v)));
}

// One-sided (Hestenes) Jacobi, circle-method tournament pairing (convergence
// verified in R2: absmax at the bf16 quantization floor). Main loop: registers
// + ds_bpermute only, no LDS, no barriers. Epilogue: chunked 16-column LDS
// transpose (4 passes), ~5.4 KB LDS.
// __launch_bounds__(64, 3): VGPR cap ~170 — fits x[64]+xp[64]+temps (~150)
// with NO spill. (64,8) would cap at 64 VGPRs -> catastrophic scratch spill;
// that is what killed the R3 bench.
__global__ __launch_bounds__(64, 3) void logeig_kernel(
    const float* __restrict__ Xg, float* __restrict__ out)
{
    __shared__ __align__(16) float Wc[64 * 20];  // 16-col chunk, rows padded to 20
    __shared__ float hlds[64];

    const int lane = threadIdx.x;
    const int b = blockIdx.x;

    // ---- load column `lane` of X; X is symmetric so read ROW `lane` (float4) ----
    float x[64];
    {
        const float4* __restrict__ Xb4 = (const float4*)(Xg + (size_t)b * 4096);
        #pragma unroll
        for (int q = 0; q < 16; ++q) {
            float4 v = Xb4[lane * 16 + q];
            x[4 * q + 0] = v.x; x[4 * q + 1] = v.y;
            x[4 * q + 2] = v.z; x[4 * q + 3] = v.w;
        }
    }

    // ---- initial squared norm alpha ----
    float d;
    {
        float a0 = 0.f, a1 = 0.f, a2 = 0.f, a3 = 0.f;
        #pragma unroll
        for (int k = 0; k < 64; k += 4) {
            a0 = fmaf(x[k + 0], x[k + 0], a0);
            a1 = fmaf(x[k + 1], x[k + 1], a1);
            a2 = fmaf(x[k + 2], x[k + 2], a2);
            a3 = fmaf(x[k + 3], x[k + 3], a3);
        }
        d = (a0 + a1) + (a2 + a3);
    }

    // ---- tournament state (identical to verified R2) ----
    const int m  = lane - 1;                       // label; -1 for fixed player lane 0
    int pm = (lane == 0) ? 0 : ((63 - m) % 63);    // (r - m) mod 63 at r=0
    int p0 = 0;                                    // 32*r mod 63

    for (int sweep = 0; sweep < NSW; ++sweep) {
        for (int r = 0; r < 63; ++r) {
            const int prt  = (lane == 0) ? (p0 + 1)
                                         : ((pm == m) ? 0 : (pm + 1));
            const int prt4 = prt << 2;

            // fetch partner column once + Gram dot product
            float xp[64];
            float g0 = 0.f, g1 = 0.f, g2 = 0.f, g3 = 0.f;
            #pragma unroll
            for (int k = 0; k < 64; k += 4) {
                xp[k + 0] = bperm_f(prt4, x[k + 0]);
                xp[k + 1] = bperm_f(prt4, x[k + 1]);
                xp[k + 2] = bperm_f(prt4, x[k + 2]);
                xp[k + 3] = bperm_f(prt4, x[k + 3]);
                g0 = fmaf(x[k + 0], xp[k + 0], g0);
                g1 = fmaf(x[k + 1], xp[k + 1], g1);
                g2 = fmaf(x[k + 2], xp[k + 2], g2);
                g3 = fmaf(x[k + 3], xp[k + 3], g3);
            }
            // pin xp in VGPRs: volatile asm cannot be rematerialized, so the
            // allocator may NOT re-issue the 64 bpermutes for the update pass.
            #pragma unroll
            for (int k = 0; k < 64; ++k) asm volatile("" : "+v"(xp[k]));

            const float g  = (g0 + g1) + (g2 + g3);   // gamma: bit-identical on both lanes
            const float dq = bperm_f(prt4, d);        // partner's squared norm
            const bool  lo = lane < prt;
            const bool  ok = fabsf(g) > 1e-30f;

            // angle from the LO lane's perspective (identical arithmetic both sides)
            const float num  = lo ? (dq - d) : (d - dq);
            const float zeta = num / (2.f * g);
            const float az   = fabsf(zeta);
            float tl = 1.f / (az + sqrtf(fmaf(az, az, 1.f)));
            tl = (zeta >= 0.f) ? tl : -tl;            // lo-side t
            float tn = lo ? tl : -tl;                 // own signed t (hi negates)
            tn = ok ? tn : 0.f;
            const float c = rsqrtf(fmaf(tn, tn, 1.f));
            const float s = c * tn;

            // Rutishauser norm update: alpha' = alpha - t_own * gamma
            d = fmaf(-tn, g, d);

            // column update: u' = c*u - s_own*u_partner
            #pragma unroll
            for (int k = 0; k < 64; ++k)
                x[k] = fmaf(-s, xp[k], c * x[k]);

            // advance tournament state
            pm = (pm + 1 == 63) ? 0 : (pm + 1);
            p0 += 32; if (p0 >= 63) p0 -= 63;
        }

        // sweep boundary: resync squared norm (kills Rutishauser drift)
        float a0 = 0.f, a1 = 0.f, a2 = 0.f, a3 = 0.f;
        #pragma unroll
        for (int k = 0; k < 64; k += 4) {
            a0 = fmaf(x[k + 0], x[k + 0], a0);
            a1 = fmaf(x[k + 1], x[k + 1], a1);
            a2 = fmaf(x[k + 2], x[k + 2], a2);
            a3 = fmaf(x[k + 3], x[k + 3], a3);
        }
        d = (a0 + a1) + (a2 + a3);
    }

    // ---- epilogue: out = sum_l h_l * w_l w_l^T, 16 columns at a time ----
    const float alpha = fmaxf(d, 1e-12f);
    const float h = 0.5f * logf(alpha) / alpha;
    hlds[lane] = h;

    float acc[64];
    #pragma unroll
    for (int i = 0; i < 64; ++i) acc[i] = 0.f;

    const int cg = lane >> 4;   // which chunk this lane's column belongs to
    const int cc = lane & 15;   // column index within the chunk

    for (int gi = 0; gi < 4; ++gi) {
        // deposit: lanes of chunk gi write their column (16 distinct banks -> free)
        if (cg == gi) {
            #pragma unroll
            for (int k = 0; k < 64; ++k) Wc[k * 20 + cc] = x[k];
        }
        __syncthreads();

        // r0[j] = h_{16gi+j} * w_{16gi+j}[lane]
        float r0[16];
        #pragma unroll
        for (int j = 0; j < 16; ++j) r0[j] = Wc[lane * 20 + j] * hlds[gi * 16 + j];

        // acc[i] += sum_j Wc[i][j] * r0[j]  (uniform b128 broadcast reads)
        #pragma unroll
        for (int i = 0; i < 64; ++i) {
            const float4 wa = *(const float4*)&Wc[i * 20 + 0];
            const float4 wb = *(const float4*)&Wc[i * 20 + 4];
            const float4 wc = *(const float4*)&Wc[i * 20 + 8];
            const float4 wd = *(const float4*)&Wc[i * 20 + 12];
            float t0 = fmaf(wa.x, r0[0],  fmaf(wa.y, r0[1],  fmaf(wa.z, r0[2],  wa.w * r0[3])));
            float t1 = fmaf(wb.x, r0[4],  fmaf(wb.y, r0[5],  fmaf(wb.z, r0[6],  wb.w * r0[7])));
            float t2 = fmaf(wc.x, r0[8],  fmaf(wc.y, r0[9],  fmaf(wc.z, r0[10], wc.w * r0[11])));
            float t3 = fmaf(wd.x, r0[12], fmaf(wd.y, r0[13], fmaf(wd.z, r0[14], wd.w * r0[15])));
            acc[i] += (t0 + t1) + (t2 + t3);
        }
        __syncthreads();   // before next chunk overwrites Wc
    }

    // coalesced stores
    float* __restrict__ outb = out + (size_t)b * 4096;
    #pragma unroll
    for (int i = 0; i < 64; ++i) outb[i * 64 + lane] = acc[i];
}

extern "C" void kernel_launch(void* const* d_in, const int* in_sizes, int n_in,
                              void* d_out, int out_size, void* d_ws, size_t ws_size,
                              hipStream_t stream)
{
    const float* X = (const float*)d_in[0];
    float* out = (float*)d_out;
    const int B = in_sizes[0] / 4096;   // 8192 matrices of 64x64 fp32
    logeig_kernel<<<dim3(B), dim3(64), 0, stream>>>(X, out);
}

// Round 5
// 5123.441 us; speedup vs baseline: 1.3749x; 1.3749x over previous
//
#include <hip/hip_runtime.h>
#include <math.h>

#define NSW 12  // convergence-verified budget (R2: absmax at bf16 floor)

__device__ __forceinline__ float bperm_f(int addr4, float v) {
    return __int_as_float(__builtin_amdgcn_ds_bpermute(addr4, __float_as_int(v)));
}

// One-sided (Hestenes) Jacobi, circle-method tournament pairing (R2-verified),
// with each matrix split across TWO waves: wave w owns rows [32w,32w+32) of
// all 64 columns; lane l holds a 32-float half-column. Live set ~75 VGPRs --
// comfortably under the allocator's observed 84-reg preference, so no
// rematerialized bpermutes (R2: +64 DS/rot) and no scratch spill (R4: +117MB).
// DS ops per matrix-rotation: 2*(32 fetch + 1 gram-write + 1 gram-read +
// 1 norm-bperm) = 70 vs R2's ~130.
// Cross-wave Gram partials: gamma = S_top + S_bot, exchanged via a
// round-parity double-buffered LDS slot (one barrier per rotation; WAR safety
// from the next rotation's barrier). Bitwise pair/wave consistency: the two
// partials are shared verbatim, and IEEE add/mul commutativity makes
// gamma = gp + go identical on all four copies of the pair.
__global__ __launch_bounds__(128, 4) void logeig_kernel(
    const float* __restrict__ Xg, float* __restrict__ out)
{
    __shared__ __align__(16) float Wc[64 * 20];  // epilogue chunk (16 cols, pad 20)
    __shared__ float gbuf[2][2][64];             // [round&1][wave][column] gram partials
    __shared__ float nbuf[2][64];                // [wave][column] norm resync
    __shared__ float hlds[64];

    const int tid = threadIdx.x;
    const int w   = tid >> 6;     // 0: rows 0-31, 1: rows 32-63
    const int l   = tid & 63;     // owned column
    const int b   = blockIdx.x;

    // ---- load rows [32w,32w+32) of column l; X symmetric -> column l == row l,
    // so read the row-major contiguous span X[b][l][32w..32w+32) as 8x float4 ----
    float x[32];
    {
        const float4* __restrict__ Xb4 =
            (const float4*)(Xg + (size_t)b * 4096 + (size_t)l * 64 + 32 * w);
        #pragma unroll
        for (int q = 0; q < 8; ++q) {
            float4 v = Xb4[q];
            x[4 * q + 0] = v.x; x[4 * q + 1] = v.y;
            x[4 * q + 2] = v.z; x[4 * q + 3] = v.w;
        }
    }

    // ---- initial squared norm: half-norms combined across waves ----
    float d;
    {
        float a0 = 0.f, a1 = 0.f, a2 = 0.f, a3 = 0.f;
        #pragma unroll
        for (int k = 0; k < 32; k += 4) {
            a0 = fmaf(x[k + 0], x[k + 0], a0);
            a1 = fmaf(x[k + 1], x[k + 1], a1);
            a2 = fmaf(x[k + 2], x[k + 2], a2);
            a3 = fmaf(x[k + 3], x[k + 3], a3);
        }
        nbuf[w][l] = (a0 + a1) + (a2 + a3);
        __syncthreads();
        d = nbuf[0][l] + nbuf[1][l];   // canonical top+bot, identical on both waves
    }

    // ---- tournament state (identical formulas to R2, per column l) ----
    const int m  = l - 1;                       // label; -1 for fixed player col 0
    int pm = (l == 0) ? 0 : ((63 - m) % 63);    // (r - m) mod 63 at r=0
    int p0 = 0;                                 // 32*r mod 63

    for (int sweep = 0; sweep < NSW; ++sweep) {
        for (int r = 0; r < 63; ++r) {
            const int prt  = (l == 0) ? (p0 + 1)
                                      : ((pm == m) ? 0 : (pm + 1));
            const int prt4 = prt << 2;

            // fetch partner half-column + Gram partial (this wave's 32 rows)
            float xp[32];
            float g0 = 0.f, g1 = 0.f, g2 = 0.f, g3 = 0.f;
            #pragma unroll
            for (int k = 0; k < 32; k += 4) {
                xp[k + 0] = bperm_f(prt4, x[k + 0]);
                xp[k + 1] = bperm_f(prt4, x[k + 1]);
                xp[k + 2] = bperm_f(prt4, x[k + 2]);
                xp[k + 3] = bperm_f(prt4, x[k + 3]);
                g0 = fmaf(x[k + 0], xp[k + 0], g0);
                g1 = fmaf(x[k + 1], xp[k + 1], g1);
                g2 = fmaf(x[k + 2], xp[k + 2], g2);
                g3 = fmaf(x[k + 3], xp[k + 3], g3);
            }
            const float gp = (g0 + g1) + (g2 + g3);  // this wave's half of gamma
            const float dq = bperm_f(prt4, d);       // partner's full norm (replicated)

            gbuf[r & 1][w][l] = gp;
            __syncthreads();
            const float go = gbuf[r & 1][1 - w][l];
            const float g  = gp + go;                // commutative -> bit-identical

            const bool lo = l < prt;
            const bool ok = fabsf(g) > 1e-30f;

            // angle from the LO column's perspective (identical on all copies)
            const float num  = lo ? (dq - d) : (d - dq);
            const float zeta = num / (2.f * g);
            const float az   = fabsf(zeta);
            float tl = 1.f / (az + sqrtf(fmaf(az, az, 1.f)));
            tl = (zeta >= 0.f) ? tl : -tl;           // lo-side t
            float tn = lo ? tl : -tl;                // own signed t (hi negates)
            tn = ok ? tn : 0.f;
            const float c = rsqrtf(fmaf(tn, tn, 1.f));
            const float s = c * tn;

            // Rutishauser norm update (identical on both waves)
            d = fmaf(-tn, g, d);

            // half-column update
            #pragma unroll
            for (int k = 0; k < 32; ++k)
                x[k] = fmaf(-s, xp[k], c * x[k]);

            // advance tournament state
            pm = (pm + 1 == 63) ? 0 : (pm + 1);
            p0 += 32; if (p0 >= 63) p0 -= 63;
        }

        // sweep boundary: resync squared norm from actual half-norms
        float a0 = 0.f, a1 = 0.f, a2 = 0.f, a3 = 0.f;
        #pragma unroll
        for (int k = 0; k < 32; k += 4) {
            a0 = fmaf(x[k + 0], x[k + 0], a0);
            a1 = fmaf(x[k + 1], x[k + 1], a1);
            a2 = fmaf(x[k + 2], x[k + 2], a2);
            a3 = fmaf(x[k + 3], x[k + 3], a3);
        }
        __syncthreads();                        // rotations' gbuf reads done before reuse window
        nbuf[w][l] = (a0 + a1) + (a2 + a3);
        __syncthreads();
        d = nbuf[0][l] + nbuf[1][l];
    }

    // ---- epilogue: out = sum_l h_l * w_l w_l^T, 16 columns per chunk ----
    const float alpha = fmaxf(d, 1e-12f);
    const float h = 0.5f * logf(alpha) / alpha;
    if (w == 0) hlds[l] = h;

    float acc[32];
    #pragma unroll
    for (int j = 0; j < 32; ++j) acc[j] = 0.f;

    const int cg = l >> 4;   // chunk containing this lane's column
    const int cc = l & 15;   // column index within chunk

    for (int gi = 0; gi < 4; ++gi) {
        __syncthreads();     // orders hlds (gi=0) / protects Wc WAR (gi>0)
        if (cg == gi) {
            #pragma unroll
            for (int j = 0; j < 32; ++j) Wc[(32 * w + j) * 20 + cc] = x[j];
        }
        __syncthreads();

        // r0[jj] = h_{16gi+jj} * w_{16gi+jj}[l]
        float r0[16];
        #pragma unroll
        for (int jj = 0; jj < 16; ++jj) r0[jj] = Wc[l * 20 + jj] * hlds[gi * 16 + jj];

        // acc[j] += sum_jj Wc[32w+j][jj] * r0[jj]  (row reads uniform per wave)
        #pragma unroll
        for (int j = 0; j < 32; ++j) {
            const int row = 32 * w + j;
            const float4 wa = *(const float4*)&Wc[row * 20 + 0];
            const float4 wb = *(const float4*)&Wc[row * 20 + 4];
            const float4 wv = *(const float4*)&Wc[row * 20 + 8];
            const float4 wd = *(const float4*)&Wc[row * 20 + 12];
            float t0 = fmaf(wa.x, r0[0],  fmaf(wa.y, r0[1],  fmaf(wa.z, r0[2],  wa.w * r0[3])));
            float t1 = fmaf(wb.x, r0[4],  fmaf(wb.y, r0[5],  fmaf(wb.z, r0[6],  wb.w * r0[7])));
            float t2 = fmaf(wv.x, r0[8],  fmaf(wv.y, r0[9],  fmaf(wv.z, r0[10], wv.w * r0[11])));
            float t3 = fmaf(wd.x, r0[12], fmaf(wd.y, r0[13], fmaf(wd.z, r0[14], wd.w * r0[15])));
            acc[j] += (t0 + t1) + (t2 + t3);
        }
    }

    // coalesced stores: for fixed j, lanes l=0..63 write 256B contiguous
    float* __restrict__ outb = out + (size_t)b * 4096;
    #pragma unroll
    for (int j = 0; j < 32; ++j)
        outb[(size_t)(32 * w + j) * 64 + l] = acc[j];
}

extern "C" void kernel_launch(void* const* d_in, const int* in_sizes, int n_in,
                              void* d_out, int out_size, void* d_ws, size_t ws_size,
                              hipStream_t stream)
{
    const float* X = (const float*)d_in[0];
    float* out = (float*)d_out;
    const int B = in_sizes[0] / 4096;   // 8192 matrices of 64x64 fp32
    logeig_kernel<<<dim3(B), dim3(128), 0, stream>>>(X, out);
}